// Round 9
// baseline (250.170 us; speedup 1.0000x reference)
//
#include <hip/hip_runtime.h>
#include <math.h>

#define DIM 1024
#define HEADS 16
#define HD 64
// 0.125 (1/sqrt(64)) * log2(e): folded into Wq_eff/bq_eff so attn uses exp2
#define QSCALE 0.1803368801111204f

typedef __attribute__((ext_vector_type(8))) short short8;
typedef __attribute__((ext_vector_type(4))) float f32x4;
typedef unsigned short ushort_t;

#define MFMA(a, b, c) __builtin_amdgcn_mfma_f32_16x16x32_bf16(a, b, c, 0, 0, 0)
#define VMCNT(n) asm volatile("s_waitcnt vmcnt(" #n ")" ::: "memory")
#define LGKMCNT0() asm volatile("s_waitcnt lgkmcnt(0)" ::: "memory")
#define BARRIER() __builtin_amdgcn_s_barrier()

__device__ __forceinline__ ushort_t f2bf(float f) {
    union { float f; unsigned u; } v; v.f = f;
    unsigned r = v.u + 0x7FFF + ((v.u >> 16) & 1);
    return (ushort_t)(r >> 16);
}
__device__ __forceinline__ void gl2lds16(const void* g, void* l) {
    __builtin_amdgcn_global_load_lds(
        (const __attribute__((address_space(1))) unsigned*)g,
        (__attribute__((address_space(3))) unsigned*)l, 16, 0, 0);
}

// ===========================================================================
// prep1: blocks [0,48): T1 partials (row-major, launched FIRST so the fold
//        overlaps the cvt wave instead of tailing it).
//        blocks [48,6704): f32->bf16 of x, audio_features, a_w, o_w.
// ===========================================================================
#define C_X  1048576
#define C_AF 196608
__global__ __launch_bounds__(256) void prep1(
    const float* __restrict__ x, const float* __restrict__ af,
    const float* __restrict__ aw, const float* __restrict__ ow,
    ushort_t* __restrict__ xb, ushort_t* __restrict__ afb,
    ushort_t* __restrict__ awb, ushort_t* __restrict__ owb,
    const float* __restrict__ qw, const float* __restrict__ kw,
    const float* __restrict__ vw,
    const float* __restrict__ qA, const float* __restrict__ kA,
    const float* __restrict__ vA,
    float* __restrict__ part)                     // [48][4][1024]
{
    const int b = blockIdx.x, tid = threadIdx.x;
    if (b >= 48) {
        int c = (b - 48) * 256 + tid;
        const float* s; ushort_t* d; int off;
        if (c < C_X)               { s = x;  d = xb;  off = c; }
        else if (c < C_X + C_AF)   { s = af; d = afb; off = c - C_X; }
        else if (c < C_X + 2*C_AF) { s = aw; d = awb; off = c - C_X - C_AF; }
        else                       { s = ow; d = owb; off = c - C_X - 2*C_AF; }
        float4 v = ((const float4*)s)[off];
        ushort4 o = { f2bf(v.x), f2bf(v.y), f2bf(v.z), f2bf(v.w) };
        ((ushort4*)d)[off] = o;
        return;
    }
    const int pb = b;                              // 0..47
    const int proj = pb >> 4, chunk = pb & 15;
    const float* W = proj == 0 ? qw : proj == 1 ? kw : vw;
    const float* A = proj == 0 ? qA : proj == 1 ? kA : vA;
    const float4* W4 = (const float4*)W;

    float4 acc0 = {0,0,0,0}, acc1 = {0,0,0,0}, acc2 = {0,0,0,0}, acc3 = {0,0,0,0};
    const int o0 = chunk * 64;
    for (int o = o0; o < o0 + 64; ++o) {
        float4 wrow = W4[o * 256 + tid];           // coalesced
        float a0 = A[o], a1 = A[1024 + o], a2 = A[2048 + o], a3 = A[3072 + o];
        acc0.x += a0 * wrow.x; acc0.y += a0 * wrow.y; acc0.z += a0 * wrow.z; acc0.w += a0 * wrow.w;
        acc1.x += a1 * wrow.x; acc1.y += a1 * wrow.y; acc1.z += a1 * wrow.z; acc1.w += a1 * wrow.w;
        acc2.x += a2 * wrow.x; acc2.y += a2 * wrow.y; acc2.z += a2 * wrow.z; acc2.w += a2 * wrow.w;
        acc3.x += a3 * wrow.x; acc3.y += a3 * wrow.y; acc3.z += a3 * wrow.z; acc3.w += a3 * wrow.w;
    }
    float4* P4 = (float4*)part;
    P4[(pb * 4 + 0) * 256 + tid] = acc0;
    P4[(pb * 4 + 1) * 256 + tid] = acc1;
    P4[(pb * 4 + 2) * 256 + tid] = acc2;
    P4[(pb * 4 + 3) * 256 + tid] = acc3;
}

// ===========================================================================
// prep2: 48 blocks (proj, chunk). Reduce 16 partials -> T1[4][1024] in LDS,
// then stream 64 W rows coalesced: W_eff=(W+0.25*B@T1)*scale -> bf16.
// chunk==0 blocks also fold b_eff=(b+0.25*B@(A@b))*scale.
// ===========================================================================
__global__ __launch_bounds__(256) void prep2(
    const float* __restrict__ qw, const float* __restrict__ kw,
    const float* __restrict__ vw,
    const float* __restrict__ qA, const float* __restrict__ kA,
    const float* __restrict__ vA,
    const float* __restrict__ qB, const float* __restrict__ kB,
    const float* __restrict__ vB,
    const float* __restrict__ qb, const float* __restrict__ kb,
    const float* __restrict__ vb,
    const float* __restrict__ part,
    ushort_t* __restrict__ wqe, ushort_t* __restrict__ wke,
    ushort_t* __restrict__ wve, float* __restrict__ beff)
{
    const int b = blockIdx.x, tid = threadIdx.x;
    const int proj = b >> 4, chunk = b & 15;
    const float* W = proj == 0 ? qw : proj == 1 ? kw : vw;
    const float* A = proj == 0 ? qA : proj == 1 ? kA : vA;
    const float* B = proj == 0 ? qB : proj == 1 ? kB : vB;
    const float* bias = proj == 0 ? qb : proj == 1 ? kb : vb;
    ushort_t* Weff = proj == 0 ? wqe : proj == 1 ? wke : wve;
    const float scale = proj == 0 ? QSCALE : 1.0f;
    const float4* W4 = (const float4*)W;
    const float4* P4 = (const float4*)part;

    __shared__ float T1s[4096];                    // [4][1024] f32, 16KB
    #pragma unroll
    for (int r = 0; r < 4; ++r) {
        float4 s = {0, 0, 0, 0};
        for (int blk = 0; blk < 16; ++blk) {
            float4 p = P4[((proj * 16 + blk) * 4 + r) * 256 + tid];
            s.x += p.x; s.y += p.y; s.z += p.z; s.w += p.w;
        }
        *(float4*)(T1s + r * 1024 + tid * 4) = s;
    }
    __syncthreads();

    float4 t0 = *(const float4*)(T1s + tid * 4);
    float4 t1 = *(const float4*)(T1s + 1024 + tid * 4);
    float4 t2 = *(const float4*)(T1s + 2048 + tid * 4);
    float4 t3 = *(const float4*)(T1s + 3072 + tid * 4);

    const int o0 = chunk * 64;
    for (int o = o0; o < o0 + 64; ++o) {
        float4 wrow = W4[o * 256 + tid];
        float4 Bo = *(const float4*)(B + o * 4);
        ushort4 out;
        out.x = f2bf((wrow.x + 0.25f * (Bo.x*t0.x + Bo.y*t1.x + Bo.z*t2.x + Bo.w*t3.x)) * scale);
        out.y = f2bf((wrow.y + 0.25f * (Bo.x*t0.y + Bo.y*t1.y + Bo.z*t2.y + Bo.w*t3.y)) * scale);
        out.z = f2bf((wrow.z + 0.25f * (Bo.x*t0.z + Bo.y*t1.z + Bo.z*t2.z + Bo.w*t3.z)) * scale);
        out.w = f2bf((wrow.w + 0.25f * (Bo.x*t0.w + Bo.y*t1.w + Bo.z*t2.w + Bo.w*t3.w)) * scale);
        *(ushort4*)(Weff + (size_t)o * 1024 + tid * 4) = out;
    }

    if (chunk == 0) {
        float bt[4] = {0.f, 0.f, 0.f, 0.f};
        for (int o = tid; o < 1024; o += 256) {
            float bo = bias[o];
            bt[0] = fmaf(A[o], bo, bt[0]);
            bt[1] = fmaf(A[1024 + o], bo, bt[1]);
            bt[2] = fmaf(A[2048 + o], bo, bt[2]);
            bt[3] = fmaf(A[3072 + o], bo, bt[3]);
        }
        #pragma unroll
        for (int r = 0; r < 4; ++r)
            #pragma unroll
            for (int off = 32; off; off >>= 1) bt[r] += __shfl_xor(bt[r], off);
        __shared__ float btr[4][4];
        if ((tid & 63) == 0) {
            #pragma unroll
            for (int r = 0; r < 4; ++r) btr[r][tid >> 6] = bt[r];
        }
        __syncthreads();
        float b0 = btr[0][0] + btr[0][1] + btr[0][2] + btr[0][3];
        float b1 = btr[1][0] + btr[1][1] + btr[1][2] + btr[1][3];
        float b2 = btr[2][0] + btr[2][1] + btr[2][2] + btr[2][3];
        float b3 = btr[3][0] + btr[3][1] + btr[3][2] + btr[3][3];
        for (int o = tid; o < 1024; o += 256) {
            float4 Bo = *(const float4*)(B + o * 4);
            beff[proj * 1024 + o] =
                (bias[o] + 0.25f * (Bo.x*b0 + Bo.y*b1 + Bo.z*b2 + Bo.w*b3)) * scale;
        }
    }
}

// ===========================================================================
// gemm3p body: 128x128 tile, 4 waves (each 64x64), BK=32, 3-deep LDS pipeline.
// Order: stage(t+2) -> MFMA(t) -> counted VMCNT -> BARRIER -> readfr(t+1).
// ===========================================================================
template<int OUTF32>
__device__ __forceinline__ void gemm3p_body(
    char* lds, const ushort_t* __restrict__ A, const ushort_t* __restrict__ W,
    const float* __restrict__ bias, void* __restrict__ C,
    int N, int K, int bm, int bn)
{
    const int tid = threadIdx.x, lane = tid & 63, wv = tid >> 6;
    const int l15 = lane & 15, l4 = lane >> 4;
    const int wm = wv >> 1, wn = wv & 1;

    const ushort_t *Ag[2], *Wg[2];
    #pragma unroll
    for (int c = 0; c < 2; ++c) {
        int f = c * 256 + tid, ra = f >> 2, ga = (f & 3) ^ ((ra >> 1) & 3);
        Ag[c] = A + (size_t)(bm * 128 + ra) * K + ga * 8;
        Wg[c] = W + (size_t)(bn * 128 + ra) * K + ga * 8;
    }
    int aoff[4], woff[4];
    #pragma unroll
    for (int m = 0; m < 4; ++m) {
        int r = wm * 64 + m * 16 + l15;
        aoff[m] = r * 64 + ((l4 ^ ((r >> 1) & 3)) << 4);
    }
    #pragma unroll
    for (int n = 0; n < 4; ++n) {
        int cc = wn * 64 + n * 16 + l15;
        woff[n] = cc * 64 + ((l4 ^ ((cc >> 1) & 3)) << 4);
    }

    auto stage = [&](char* base, int k0) {
        #pragma unroll
        for (int c = 0; c < 2; ++c) {
            gl2lds16(Ag[c] + k0, base + c * 4096 + wv * 1024);
            gl2lds16(Wg[c] + k0, base + 8192 + c * 4096 + wv * 1024);
        }
    };

    short8 fa[4], fw[4];
    auto readfr = [&](const char* base) {
        #pragma unroll
        for (int m = 0; m < 4; ++m) fa[m] = *(const short8*)(base + aoff[m]);
        #pragma unroll
        for (int n = 0; n < 4; ++n) fw[n] = *(const short8*)(base + 8192 + woff[n]);
    };

    f32x4 acc[4][4] = {};
    const int nt = K / 32;

    stage(lds, 0);
    stage(lds + 16384, 32);
    VMCNT(4);
    BARRIER();
    readfr(lds);

    int bcur = 0;
    for (int t = 0; t < nt; ++t) {
        int bnext = bcur + 1; if (bnext == 3) bnext = 0;
        int bpre  = bnext + 1; if (bpre == 3) bpre = 0;
        if (t + 2 < nt) stage(lds + bpre * 16384, (t + 2) * 32);
        #pragma unroll
        for (int m = 0; m < 4; ++m)
            #pragma unroll
            for (int n = 0; n < 4; ++n)
                acc[m][n] = MFMA(fa[m], fw[n], acc[m][n]);
        if (t + 1 < nt) {
            if (t + 2 < nt) { VMCNT(4); } else { VMCNT(0); }
            BARRIER();
            readfr(lds + bnext * 16384);
        }
        bcur = bnext;
    }

    #pragma unroll
    for (int n = 0; n < 4; ++n) {
        int gc = bn * 128 + wn * 64 + n * 16 + l15;
        float bv = bias[gc];
        #pragma unroll
        for (int m = 0; m < 4; ++m) {
            int gr = bm * 128 + wm * 64 + m * 16 + (l4 << 2);
            #pragma unroll
            for (int j = 0; j < 4; ++j) {
                float v = acc[m][n][j] + bv;
                if (OUTF32) ((float*)C)[(size_t)(gr + j) * N + gc] = v;
                else        ((ushort_t*)C)[(size_t)(gr + j) * N + gc] = f2bf(v);
            }
        }
    }
}

template<int OUTF32>
__global__ __launch_bounds__(256) void gemm3p(
    const ushort_t* __restrict__ A, const ushort_t* __restrict__ W,
    const float* __restrict__ bias, void* __restrict__ C, int N, int K)
{
    __shared__ char lds[49152];
    gemm3p_body<OUTF32>(lds, A, W, bias, C, N, K, blockIdx.y, blockIdx.x);
}

// ===========================================================================
// audio body: 64x64 tile, K=768, BK=32 dbuf, counted vmcnt (r3-validated).
// ===========================================================================
__device__ __forceinline__ void audio_body(
    char* lds, const ushort_t* __restrict__ A, const ushort_t* __restrict__ W,
    const float* __restrict__ bias, ushort_t* __restrict__ C, int bm, int bn)
{
    const int K = 768, N = DIM;
    char* As = lds;
    char* Ws = lds + 8192;
    const int tid = threadIdx.x, lane = tid & 63, wv = tid >> 6;
    const int l15 = lane & 15, l4 = lane >> 4;

    int f = tid, ra = f >> 2, ga = (f & 3) ^ ((ra >> 1) & 3);
    const ushort_t* Ag = A + (size_t)(bm * 64 + ra) * K + ga * 8;
    const ushort_t* Wg = W + (size_t)(bn * 64 + ra) * K + ga * 8;

    int aoff, woff[4];
    { int r = wv * 16 + l15; aoff = r * 64 + ((l4 ^ ((r >> 1) & 3)) << 4); }
    #pragma unroll
    for (int n = 0; n < 4; ++n) {
        int cc = n * 16 + l15;
        woff[n] = cc * 64 + ((l4 ^ ((cc >> 1) & 3)) << 4);
    }

    f32x4 acc[4] = {};
    const int nt = K / 32;
    gl2lds16(Ag, As + wv * 1024);
    gl2lds16(Wg, Ws + wv * 1024);

    for (int t = 0; t < nt; ++t) {
        const int buf = t & 1;
        if (t + 1 < nt) {
            const int k1 = (t + 1) * 32;
            gl2lds16(Ag + k1, As + (buf ^ 1) * 4096 + wv * 1024);
            gl2lds16(Wg + k1, Ws + (buf ^ 1) * 4096 + wv * 1024);
            VMCNT(2);
        } else {
            VMCNT(0);
        }
        BARRIER();
        const char* AsB = As + buf * 4096;
        const char* WsB = Ws + buf * 4096;
        short8 fa = *(const short8*)(AsB + aoff);
        short8 fw[4];
        #pragma unroll
        for (int n = 0; n < 4; ++n) fw[n] = *(const short8*)(WsB + woff[n]);
        #pragma unroll
        for (int n = 0; n < 4; ++n) acc[n] = MFMA(fa, fw[n], acc[n]);
        BARRIER();
    }

    const int gr = bm * 64 + wv * 16 + (l4 << 2);
    #pragma unroll
    for (int n = 0; n < 4; ++n) {
        int gc = bn * 64 + n * 16 + l15;
        float bb = bias[gc];
        #pragma unroll
        for (int j = 0; j < 4; ++j)
            C[(size_t)(gr + j) * N + gc] = f2bf(acc[n][j] + bb);
    }
}

// fused audio-proj (blocks 0..255) + q-proj (blocks 256..511)
__global__ __launch_bounds__(256) void fused_aq(
    const ushort_t* __restrict__ afb, const ushort_t* __restrict__ awb,
    const float* __restrict__ a_b, ushort_t* __restrict__ audio,
    const ushort_t* __restrict__ xb, const ushort_t* __restrict__ wqe,
    const float* __restrict__ beff, ushort_t* __restrict__ qbb)
{
    __shared__ char lds[49152];
    const int b = blockIdx.x;
    if (b < 256) {
        audio_body(lds, afb, awb, a_b, audio, b >> 4, b & 15);
    } else {
        const int i = b - 256;
        gemm3p_body<0>(lds, xb, wqe, beff, qbb, DIM, DIM, i >> 3, i & 7);
    }
}

// ===========================================================================
// Merged K+V projection (A=audio 1024x1024). grid (32,16): x<16 -> K half
// (row-major out), x>=16 -> V half (transposed out vt[d][key]). r4-validated.
// ===========================================================================
__global__ __launch_bounds__(256) void gemm2_kv(
    const ushort_t* __restrict__ A, const ushort_t* __restrict__ Wk,
    const ushort_t* __restrict__ Wv, const float* __restrict__ bk,
    const float* __restrict__ bv, ushort_t* __restrict__ Ck,
    ushort_t* __restrict__ CvT)
{
    const int K = DIM;
    __shared__ ushort_t As[2][64 * 32];
    __shared__ ushort_t Ws[2][64 * 32];
    const int tid = threadIdx.x, lane = tid & 63, wv = tid >> 6;
    const int l15 = lane & 15, l4 = lane >> 4;
    const int bm = blockIdx.y;
    const bool isV = blockIdx.x >= 16;
    const int bn = blockIdx.x & 15;
    const ushort_t* W = isV ? Wv : Wk;

    int f = tid, ra = f >> 2, ga = (f & 3) ^ ((ra >> 1) & 3);
    const ushort_t* Ag = A + (size_t)(bm * 64 + ra) * K + ga * 8;
    const ushort_t* Wg = W + (size_t)(bn * 64 + ra) * K + ga * 8;

    int aoff, woff[4];
    { int r = wv * 16 + l15; aoff = r * 64 + ((l4 ^ ((r >> 1) & 3)) << 4); }
    #pragma unroll
    for (int n = 0; n < 4; ++n) {
        int cc = n * 16 + l15;
        woff[n] = cc * 64 + ((l4 ^ ((cc >> 1) & 3)) << 4);
    }

    f32x4 acc[4] = {};
    const int nt = K / 32;
    gl2lds16(Ag, (char*)As + wv * 1024);
    gl2lds16(Wg, (char*)Ws + wv * 1024);

    for (int t = 0; t < nt; ++t) {
        const int buf = t & 1;
        if (t + 1 < nt) {
            const int k1 = (t + 1) * 32;
            gl2lds16(Ag + k1, (char*)As + (buf ^ 1) * 4096 + wv * 1024);
            gl2lds16(Wg + k1, (char*)Ws + (buf ^ 1) * 4096 + wv * 1024);
            VMCNT(2);
        } else {
            VMCNT(0);
        }
        BARRIER();
        const char* AsB = (const char*)As + buf * 4096;
        const char* WsB = (const char*)Ws + buf * 4096;
        short8 fa = *(const short8*)(AsB + aoff);
        short8 fw[4];
        #pragma unroll
        for (int n = 0; n < 4; ++n) fw[n] = *(const short8*)(WsB + woff[n]);
        #pragma unroll
        for (int n = 0; n < 4; ++n) acc[n] = MFMA(fa, fw[n], acc[n]);
        BARRIER();
    }

    const int gr = bm * 64 + wv * 16 + (l4 << 2);
    #pragma unroll
    for (int n = 0; n < 4; ++n) {
        int gc = bn * 64 + n * 16 + l15;
        float bb = (isV ? bv : bk)[gc];
        if (!isV) {
            #pragma unroll
            for (int j = 0; j < 4; ++j)
                Ck[(size_t)(gr + j) * DIM + gc] = f2bf(acc[n][j] + bb);
        } else {
            ushort4 o = { f2bf(acc[n][0] + bb), f2bf(acc[n][1] + bb),
                          f2bf(acc[n][2] + bb), f2bf(acc[n][3] + bb) };
            *(ushort4*)(CvT + (size_t)gc * DIM + gr) = o;
        }
    }
}

// ===========================================================================
// attn4: wave-private flash attention. 128 threads = 2 waves; block = 64
// q-rows x 1 head; wave w owns keys [w*512, w*512+512) as 16 tiles of 32,
// with its OWN K/V dbuf + P buffer (no cross-wave LDS deps in the k-loop ->
// NO barriers; vmcnt-only 2-deep pipeline). No-max softmax (exp2, QSCALE
// pre-folded) makes the cross-wave combine a pure sum in the epilogue.
// ===========================================================================
__global__ __launch_bounds__(128) void attn4(
    const ushort_t* __restrict__ Qf, const ushort_t* __restrict__ Kf,
    const ushort_t* __restrict__ Vt, ushort_t* __restrict__ AO)
{
    __shared__ char lds[41472];
    // [0,16384): K dbuf  (wave w at +w*8192, buf b at +b*4096)  | epilogue: O_part [2][64][64] f32
    // [16384,32768): V dbuf (same layout)                        | (overlaid)
    // [32768,40960): P per-wave 64x32 bf16 (4KB each)
    // [40960,41472): l_arr[2][64] f32
    char* KL = lds;
    char* VL = lds + 16384;
    char* PL = lds + 32768;
    float* l_arr = (float*)(lds + 40960);

    const int tid = threadIdx.x, lane = tid & 63, w = tid >> 6;
    const int l15 = lane & 15, l4 = lane >> 4;
    const int h = blockIdx.y, qb = blockIdx.x;
    const int key_base = w * 512;

    // Q fragments direct from global (L2-hot, one-time)
    short8 fq[4][2];
    #pragma unroll
    for (int m = 0; m < 4; ++m)
        #pragma unroll
        for (int ks = 0; ks < 2; ++ks)
            fq[m][ks] = *(const short8*)(
                Qf + (size_t)(qb * 64 + m * 16 + l15) * DIM + h * HD + (ks * 4 + l4) * 8);

    char* Kw = KL + w * 8192;
    char* Vw = VL + w * 8192;
    char* Pw = PL + w * 4096;

    // staging lambdas: pre-swizzled global source, linear LDS dest
    auto stageK = [&](int t, int buf) {
        int k0 = key_base + t * 32;
        #pragma unroll
        for (int i = 0; i < 4; ++i) {
            int f = i * 64 + lane, row = f >> 3, s = (f & 7) ^ (row & 7);
            gl2lds16(Kf + (size_t)(k0 + row) * DIM + h * HD + s * 8,
                     Kw + buf * 4096 + i * 1024);
        }
    };
    auto stageV = [&](int t, int buf) {
        int k0 = key_base + t * 32;
        #pragma unroll
        for (int i = 0; i < 4; ++i) {
            int f = i * 64 + lane, row = f >> 2, s = (f & 3) ^ ((row >> 1) & 3);
            gl2lds16(Vt + (size_t)(h * HD + row) * DIM + k0 + s * 8,
                     Vw + buf * 4096 + i * 1024);
        }
    };

    // fragment byte offsets
    int koff[2][2], voff[4], poffR[4];
    #pragma unroll
    for (int n = 0; n < 2; ++n) {
        int kk = n * 16 + l15;
        #pragma unroll
        for (int ks = 0; ks < 2; ++ks)
            koff[n][ks] = kk * 128 + (((ks * 4 + l4) ^ (kk & 7)) << 4);
    }
    #pragma unroll
    for (int dn = 0; dn < 4; ++dn) {
        int d = dn * 16 + l15;
        voff[dn] = d * 64 + ((l4 ^ ((d >> 1) & 3)) << 4);
    }
    #pragma unroll
    for (int m = 0; m < 4; ++m) {
        int r = m * 16 + l15;
        poffR[m] = r * 64 + ((l4 ^ ((r >> 1) & 3)) << 4);
    }

    f32x4 acc_o[4][4] = {};          // [m][dn]
    float l_loc[4][4] = {};          // [m][j]

    stageK(0, 0); stageV(0, 0);
    stageK(1, 1); stageV(1, 1);

    for (int t = 0; t < 16; ++t) {
        const int buf = t & 1;
        if (t < 15) { VMCNT(8); } else { VMCNT(0); }   // stage(t) landed; t+1 in flight
        const char* Kb = Kw + buf * 4096;
        const char* Vb = Vw + buf * 4096;

        short8 fk[2][2];
        #pragma unroll
        for (int n = 0; n < 2; ++n)
            #pragma unroll
            for (int ks = 0; ks < 2; ++ks)
                fk[n][ks] = *(const short8*)(Kb + koff[n][ks]);

        // per m: QK (4 MFMA) -> exp2 -> P write
        #pragma unroll
        for (int m = 0; m < 4; ++m) {
            f32x4 s0 = {}, s1 = {};
            s0 = MFMA(fq[m][0], fk[0][0], s0);
            s0 = MFMA(fq[m][1], fk[0][1], s0);
            s1 = MFMA(fq[m][0], fk[1][0], s1);
            s1 = MFMA(fq[m][1], fk[1][1], s1);
            #pragma unroll
            for (int j = 0; j < 4; ++j) {
                float p0 = exp2f(s0[j]);
                float p1 = exp2f(s1[j]);
                l_loc[m][j] += p0 + p1;
                int row = m * 16 + (l4 << 2) + j;
                int swz = (row >> 1) & 3;
                int b0 = row * 64 + ((((l15 >> 3)) ^ swz) << 4) + (l15 & 7) * 2;
                int b1 = row * 64 + ((((16 + l15) >> 3) ^ swz) << 4) + (l15 & 7) * 2;
                *(ushort_t*)(Pw + b0) = f2bf(p0);
                *(ushort_t*)(Pw + b1) = f2bf(p1);
            }
        }

        LGKMCNT0();                      // P writes committed (wave-local RAW)
        short8 fv[4];
        #pragma unroll
        for (int dn = 0; dn < 4; ++dn)
            fv[dn] = *(const short8*)(Vb + voff[dn]);
        #pragma unroll
        for (int m = 0; m < 4; ++m) {
            short8 pa = *(const short8*)(Pw + poffR[m]);
            #pragma unroll
            for (int dn = 0; dn < 4; ++dn)
                acc_o[m][dn] = MFMA(pa, fv[dn], acc_o[m][dn]);
        }

        if (t + 2 < 16) {
            // WAR fence: all ds_reads of this buf retired before overwrite
            LGKMCNT0();
            __builtin_amdgcn_sched_barrier(0);
            stageK(t + 2, buf); stageV(t + 2, buf);
        }
    }

    // ---- epilogue: per-wave l row-sums, then cross-wave pure-sum combine ----
    #pragma unroll
    for (int m = 0; m < 4; ++m)
        #pragma unroll
        for (int j = 0; j < 4; ++j) {
            float l = l_loc[m][j];
            l += __shfl_xor(l, 1);
            l += __shfl_xor(l, 2);
            l += __shfl_xor(l, 4);
            l += __shfl_xor(l, 8);
            if (l15 == 0) l_arr[w * 64 + m * 16 + (l4 << 2) + j] = l;
        }
    __syncthreads();                 // all compute + l writes done; K/V area dead
    float* OP = (float*)lds;         // [2][64][64]
    #pragma unroll
    for (int m = 0; m < 4; ++m)
        #pragma unroll
        for (int dn = 0; dn < 4; ++dn)
            #pragma unroll
            for (int j = 0; j < 4; ++j)
                OP[w * 4096 + (m * 16 + (l4 << 2) + j) * 64 + dn * 16 + l15] =
                    acc_o[m][dn][j];
    __syncthreads();
    for (int rr = 0; rr < 32; ++rr) {
        int row = w * 32 + rr;
        float o = OP[row * 64 + lane] + OP[4096 + row * 64 + lane];
        float lt = l_arr[row] + l_arr[64 + row];
        AO[(size_t)(qb * 64 + row) * DIM + h * HD + lane] = f2bf(o / lt);
    }
}

// ===========================================================================
extern "C" void kernel_launch(void* const* d_in, const int* in_sizes, int n_in,
                              void* d_out, int out_size, void* d_ws, size_t ws_size,
                              hipStream_t stream)
{
    const float* x   = (const float*)d_in[0];
    const float* af  = (const float*)d_in[1];
    const float* q_w = (const float*)d_in[2];
    const float* q_b = (const float*)d_in[3];
    const float* k_w = (const float*)d_in[4];
    const float* k_b = (const float*)d_in[5];
    const float* v_w = (const float*)d_in[6];
    const float* v_b = (const float*)d_in[7];
    const float* o_w = (const float*)d_in[8];
    const float* o_b = (const float*)d_in[9];
    const float* a_w = (const float*)d_in[10];
    const float* a_b = (const float*)d_in[11];
    const float* qA  = (const float*)d_in[12];
    const float* qB  = (const float*)d_in[13];
    const float* kA  = (const float*)d_in[14];
    const float* kB  = (const float*)d_in[15];
    const float* vA  = (const float*)d_in[16];
    const float* vB  = (const float*)d_in[17];
    float* out = (float*)d_out;

    const int N = 4096;

    char* w = (char*)d_ws;
    auto alloc = [&](size_t bytes) {
        char* p = w; w += (bytes + 255) & ~(size_t)255; return p;
    };
    ushort_t* xb   = (ushort_t*)alloc((size_t)N * DIM * 2);
    ushort_t* afb  = (ushort_t*)alloc((size_t)1024 * 768 * 2);
    ushort_t* awb  = (ushort_t*)alloc((size_t)DIM * 768 * 2);
    ushort_t* owb  = (ushort_t*)alloc((size_t)DIM * DIM * 2);
    ushort_t* wqe  = (ushort_t*)alloc((size_t)DIM * DIM * 2);
    ushort_t* wke  = (ushort_t*)alloc((size_t)DIM * DIM * 2);
    ushort_t* wve  = (ushort_t*)alloc((size_t)DIM * DIM * 2);
    ushort_t* audio= (ushort_t*)alloc((size_t)1024 * DIM * 2);
    ushort_t* qbb  = (ushort_t*)alloc((size_t)N * DIM * 2);
    ushort_t* kbb  = (ushort_t*)alloc((size_t)1024 * DIM * 2);
    ushort_t* vt   = (ushort_t*)alloc((size_t)1024 * DIM * 2);
    ushort_t* ao   = (ushort_t*)alloc((size_t)N * DIM * 2);
    float* part = (float*)alloc((size_t)48 * 4 * 1024 * 4);
    float* beff = (float*)alloc((size_t)3 * 1024 * 4);

    // 1. T1 partials (first) + conversions
    prep1<<<6704, 256, 0, stream>>>(
        x, af, a_w, o_w, xb, afb, awb, owb,
        q_w, k_w, v_w, qA, kA, vA, part);
    // 2. LoRA weight fold apply (QSCALE folded into q)
    prep2<<<48, 256, 0, stream>>>(
        q_w, k_w, v_w, qA, kA, vA, qB, kB, vB, q_b, k_b, v_b,
        part, wqe, wke, wve, beff);
    // 3. audio projection (blocks 0-255) || q projection (blocks 256-511)
    fused_aq<<<512, 256, 0, stream>>>(afb, awb, a_b, audio, xb, wqe, beff, qbb);
    // 4. k,v projections (v transposed)
    gemm2_kv<<<dim3(32, 16), 256, 0, stream>>>(audio, wke, wve,
                                               beff + 1024, beff + 2048, kbb, vt);
    // 5. attention (wave-private keys, barrier-free k-loop)
    attn4<<<dim3(N / 64, HEADS), 128, 0, stream>>>(qbb, kbb, vt, ao);
    // 6. output projection (f32 out)
    gemm3p<1><<<dim3(8, 32), 256, 0, stream>>>(ao, owb, o_b, out, DIM, DIM);
}

// Round 10
// 229.699 us; speedup vs baseline: 1.0891x; 1.0891x over previous
//
#include <hip/hip_runtime.h>
#include <math.h>

#define DIM 1024
#define HEADS 16
#define HD 64
// 0.125 (1/sqrt(64)) * log2(e): folded into Wq_eff/bq_eff so attn uses exp2
#define QSCALE 0.1803368801111204f

typedef __attribute__((ext_vector_type(8))) short short8;
typedef __attribute__((ext_vector_type(4))) float f32x4;
typedef unsigned short ushort_t;

#define MFMA(a, b, c) __builtin_amdgcn_mfma_f32_16x16x32_bf16(a, b, c, 0, 0, 0)
#define VMCNT(n) asm volatile("s_waitcnt vmcnt(" #n ")" ::: "memory")
#define BARRIER() __builtin_amdgcn_s_barrier()

__device__ __forceinline__ ushort_t f2bf(float f) {
    union { float f; unsigned u; } v; v.f = f;
    unsigned r = v.u + 0x7FFF + ((v.u >> 16) & 1);
    return (ushort_t)(r >> 16);
}
__device__ __forceinline__ void gl2lds16(const void* g, void* l) {
    __builtin_amdgcn_global_load_lds(
        (const __attribute__((address_space(1))) unsigned*)g,
        (__attribute__((address_space(3))) unsigned*)l, 16, 0, 0);
}

// ===========================================================================
// prep1: blocks [0,48): T1 partials (row-major, fold-first so it overlaps cvt)
//        blocks [48,6704): f32->bf16 of x, audio_features, a_w, o_w.
// ===========================================================================
#define C_X  1048576
#define C_AF 196608
__global__ __launch_bounds__(256) void prep1(
    const float* __restrict__ x, const float* __restrict__ af,
    const float* __restrict__ aw, const float* __restrict__ ow,
    ushort_t* __restrict__ xb, ushort_t* __restrict__ afb,
    ushort_t* __restrict__ awb, ushort_t* __restrict__ owb,
    const float* __restrict__ qw, const float* __restrict__ kw,
    const float* __restrict__ vw,
    const float* __restrict__ qA, const float* __restrict__ kA,
    const float* __restrict__ vA,
    float* __restrict__ part)                     // [48][4][1024]
{
    const int b = blockIdx.x, tid = threadIdx.x;
    if (b >= 48) {
        int c = (b - 48) * 256 + tid;
        const float* s; ushort_t* d; int off;
        if (c < C_X)               { s = x;  d = xb;  off = c; }
        else if (c < C_X + C_AF)   { s = af; d = afb; off = c - C_X; }
        else if (c < C_X + 2*C_AF) { s = aw; d = awb; off = c - C_X - C_AF; }
        else                       { s = ow; d = owb; off = c - C_X - 2*C_AF; }
        float4 v = ((const float4*)s)[off];
        ushort4 o = { f2bf(v.x), f2bf(v.y), f2bf(v.z), f2bf(v.w) };
        ((ushort4*)d)[off] = o;
        return;
    }
    const int pb = b;
    const int proj = pb >> 4, chunk = pb & 15;
    const float* W = proj == 0 ? qw : proj == 1 ? kw : vw;
    const float* A = proj == 0 ? qA : proj == 1 ? kA : vA;
    const float4* W4 = (const float4*)W;

    float4 acc0 = {0,0,0,0}, acc1 = {0,0,0,0}, acc2 = {0,0,0,0}, acc3 = {0,0,0,0};
    const int o0 = chunk * 64;
    for (int o = o0; o < o0 + 64; ++o) {
        float4 wrow = W4[o * 256 + tid];
        float a0 = A[o], a1 = A[1024 + o], a2 = A[2048 + o], a3 = A[3072 + o];
        acc0.x += a0 * wrow.x; acc0.y += a0 * wrow.y; acc0.z += a0 * wrow.z; acc0.w += a0 * wrow.w;
        acc1.x += a1 * wrow.x; acc1.y += a1 * wrow.y; acc1.z += a1 * wrow.z; acc1.w += a1 * wrow.w;
        acc2.x += a2 * wrow.x; acc2.y += a2 * wrow.y; acc2.z += a2 * wrow.z; acc2.w += a2 * wrow.w;
        acc3.x += a3 * wrow.x; acc3.y += a3 * wrow.y; acc3.z += a3 * wrow.z; acc3.w += a3 * wrow.w;
    }
    float4* P4 = (float4*)part;
    P4[(pb * 4 + 0) * 256 + tid] = acc0;
    P4[(pb * 4 + 1) * 256 + tid] = acc1;
    P4[(pb * 4 + 2) * 256 + tid] = acc2;
    P4[(pb * 4 + 3) * 256 + tid] = acc3;
}

// ===========================================================================
// prep2: 48 blocks (proj, chunk). Reduce partials -> T1 in LDS, stream W rows
// coalesced: W_eff=(W+0.25*B@T1)*scale -> bf16. chunk==0 also folds b_eff.
// ===========================================================================
__global__ __launch_bounds__(256) void prep2(
    const float* __restrict__ qw, const float* __restrict__ kw,
    const float* __restrict__ vw,
    const float* __restrict__ qA, const float* __restrict__ kA,
    const float* __restrict__ vA,
    const float* __restrict__ qB, const float* __restrict__ kB,
    const float* __restrict__ vB,
    const float* __restrict__ qb, const float* __restrict__ kb,
    const float* __restrict__ vb,
    const float* __restrict__ part,
    ushort_t* __restrict__ wqe, ushort_t* __restrict__ wke,
    ushort_t* __restrict__ wve, float* __restrict__ beff)
{
    const int b = blockIdx.x, tid = threadIdx.x;
    const int proj = b >> 4, chunk = b & 15;
    const float* W = proj == 0 ? qw : proj == 1 ? kw : vw;
    const float* A = proj == 0 ? qA : proj == 1 ? kA : vA;
    const float* B = proj == 0 ? qB : proj == 1 ? kB : vB;
    const float* bias = proj == 0 ? qb : proj == 1 ? kb : vb;
    ushort_t* Weff = proj == 0 ? wqe : proj == 1 ? wke : wve;
    const float scale = proj == 0 ? QSCALE : 1.0f;
    const float4* W4 = (const float4*)W;
    const float4* P4 = (const float4*)part;

    __shared__ float T1s[4096];
    #pragma unroll
    for (int r = 0; r < 4; ++r) {
        float4 s = {0, 0, 0, 0};
        for (int blk = 0; blk < 16; ++blk) {
            float4 p = P4[((proj * 16 + blk) * 4 + r) * 256 + tid];
            s.x += p.x; s.y += p.y; s.z += p.z; s.w += p.w;
        }
        *(float4*)(T1s + r * 1024 + tid * 4) = s;
    }
    __syncthreads();

    float4 t0 = *(const float4*)(T1s + tid * 4);
    float4 t1 = *(const float4*)(T1s + 1024 + tid * 4);
    float4 t2 = *(const float4*)(T1s + 2048 + tid * 4);
    float4 t3 = *(const float4*)(T1s + 3072 + tid * 4);

    const int o0 = chunk * 64;
    for (int o = o0; o < o0 + 64; ++o) {
        float4 wrow = W4[o * 256 + tid];
        float4 Bo = *(const float4*)(B + o * 4);
        ushort4 out;
        out.x = f2bf((wrow.x + 0.25f * (Bo.x*t0.x + Bo.y*t1.x + Bo.z*t2.x + Bo.w*t3.x)) * scale);
        out.y = f2bf((wrow.y + 0.25f * (Bo.x*t0.y + Bo.y*t1.y + Bo.z*t2.y + Bo.w*t3.y)) * scale);
        out.z = f2bf((wrow.z + 0.25f * (Bo.x*t0.z + Bo.y*t1.z + Bo.z*t2.z + Bo.w*t3.z)) * scale);
        out.w = f2bf((wrow.w + 0.25f * (Bo.x*t0.w + Bo.y*t1.w + Bo.z*t2.w + Bo.w*t3.w)) * scale);
        *(ushort4*)(Weff + (size_t)o * 1024 + tid * 4) = out;
    }

    if (chunk == 0) {
        float bt[4] = {0.f, 0.f, 0.f, 0.f};
        for (int o = tid; o < 1024; o += 256) {
            float bo = bias[o];
            bt[0] = fmaf(A[o], bo, bt[0]);
            bt[1] = fmaf(A[1024 + o], bo, bt[1]);
            bt[2] = fmaf(A[2048 + o], bo, bt[2]);
            bt[3] = fmaf(A[3072 + o], bo, bt[3]);
        }
        #pragma unroll
        for (int r = 0; r < 4; ++r)
            #pragma unroll
            for (int off = 32; off; off >>= 1) bt[r] += __shfl_xor(bt[r], off);
        __shared__ float btr[4][4];
        if ((tid & 63) == 0) {
            #pragma unroll
            for (int r = 0; r < 4; ++r) btr[r][tid >> 6] = bt[r];
        }
        __syncthreads();
        float b0 = btr[0][0] + btr[0][1] + btr[0][2] + btr[0][3];
        float b1 = btr[1][0] + btr[1][1] + btr[1][2] + btr[1][3];
        float b2 = btr[2][0] + btr[2][1] + btr[2][2] + btr[2][3];
        float b3 = btr[3][0] + btr[3][1] + btr[3][2] + btr[3][3];
        for (int o = tid; o < 1024; o += 256) {
            float4 Bo = *(const float4*)(B + o * 4);
            beff[proj * 1024 + o] =
                (bias[o] + 0.25f * (Bo.x*b0 + Bo.y*b1 + Bo.z*b2 + Bo.w*b3)) * scale;
        }
    }
}

// ===========================================================================
// gemm4 body: 128(M) x 64(N) tile, 4 waves in 2x2 (wave = 64 rows x 32 cols,
// 8 MFMA / 6 ds_read_b128 per k-step). BK=32, 3-deep pipeline (36KB LDS ->
// grid 512 = 2 blocks/CU: doubles latency hiding vs the old 256-block 128x128).
// Order: stage(t+2) -> MFMA(t) -> counted VMCNT -> BARRIER -> readfr(t+1).
// ===========================================================================
template<int OUTF32>
__device__ __forceinline__ void gemm4_body(
    char* lds, const ushort_t* __restrict__ A, const ushort_t* __restrict__ W,
    const float* __restrict__ bias, void* __restrict__ C,
    int N, int K, int bm, int bn)
{
    const int tid = threadIdx.x, lane = tid & 63, wv = tid >> 6;
    const int l15 = lane & 15, l4 = lane >> 4;
    const int wm = wv >> 1, wn = wv & 1;

    const ushort_t *Ag[2], *Wg;
    #pragma unroll
    for (int c = 0; c < 2; ++c) {
        int f = c * 256 + tid, ra = f >> 2, ga = (f & 3) ^ ((ra >> 1) & 3);
        Ag[c] = A + (size_t)(bm * 128 + ra) * K + ga * 8;
    }
    {
        int f = tid, rb = f >> 2, gb = (f & 3) ^ ((rb >> 1) & 3);
        Wg = W + (size_t)(bn * 64 + rb) * K + gb * 8;
    }
    int aoff[4], woff[2];
    #pragma unroll
    for (int m = 0; m < 4; ++m) {
        int r = wm * 64 + m * 16 + l15;
        aoff[m] = r * 64 + ((l4 ^ ((r >> 1) & 3)) << 4);
    }
    #pragma unroll
    for (int n = 0; n < 2; ++n) {
        int cc = wn * 32 + n * 16 + l15;
        woff[n] = cc * 64 + ((l4 ^ ((cc >> 1) & 3)) << 4);
    }

    // buf layout: A 8KB @ +0, W 4KB @ +8192; buf stride 12KB; 3 bufs
    auto stage = [&](char* base, int k0) {
        gl2lds16(Ag[0] + k0, base + wv * 1024);
        gl2lds16(Ag[1] + k0, base + 4096 + wv * 1024);
        gl2lds16(Wg + k0, base + 8192 + wv * 1024);
    };

    short8 fa[4], fw[2];
    auto readfr = [&](const char* base) {
        #pragma unroll
        for (int m = 0; m < 4; ++m) fa[m] = *(const short8*)(base + aoff[m]);
        #pragma unroll
        for (int n = 0; n < 2; ++n) fw[n] = *(const short8*)(base + 8192 + woff[n]);
    };

    f32x4 acc[4][2] = {};
    const int nt = K / 32;

    stage(lds, 0);
    stage(lds + 12288, 32);
    VMCNT(3);            // own stage(0) landed (stage(1)'s 3 still in flight)
    BARRIER();           // -> all waves' stage(0) landed
    readfr(lds);

    int bcur = 0;
    for (int t = 0; t < nt; ++t) {
        int bnext = bcur + 1; if (bnext == 3) bnext = 0;
        int bpre  = bnext + 1; if (bpre == 3) bpre = 0;
        if (t + 2 < nt) stage(lds + bpre * 12288, (t + 2) * 32);
        #pragma unroll
        for (int m = 0; m < 4; ++m)
            #pragma unroll
            for (int n = 0; n < 2; ++n)
                acc[m][n] = MFMA(fa[m], fw[n], acc[m][n]);
        if (t + 1 < nt) {
            if (t + 2 < nt) { VMCNT(3); } else { VMCNT(0); }
            BARRIER();
            readfr(lds + bnext * 12288);
        }
        bcur = bnext;
    }

    #pragma unroll
    for (int n = 0; n < 2; ++n) {
        int gc = bn * 64 + wn * 32 + n * 16 + l15;
        float bv = bias[gc];
        #pragma unroll
        for (int m = 0; m < 4; ++m) {
            int gr = bm * 128 + wm * 64 + m * 16 + (l4 << 2);
            #pragma unroll
            for (int j = 0; j < 4; ++j) {
                float v = acc[m][n][j] + bv;
                if (OUTF32) ((float*)C)[(size_t)(gr + j) * N + gc] = v;
                else        ((ushort_t*)C)[(size_t)(gr + j) * N + gc] = f2bf(v);
            }
        }
    }
}

template<int OUTF32>
__global__ __launch_bounds__(256) void gemm4(
    const ushort_t* __restrict__ A, const ushort_t* __restrict__ W,
    const float* __restrict__ bias, void* __restrict__ C, int N, int K)
{
    __shared__ char lds[36864];
    gemm4_body<OUTF32>(lds, A, W, bias, C, N, K, blockIdx.y, blockIdx.x);
}

// ===========================================================================
// audio body: 64x64 tile, K=768, BK=32 dbuf, counted vmcnt (r3-validated).
// ===========================================================================
__device__ __forceinline__ void audio_body(
    char* lds, const ushort_t* __restrict__ A, const ushort_t* __restrict__ W,
    const float* __restrict__ bias, ushort_t* __restrict__ C, int bm, int bn)
{
    const int K = 768, N = DIM;
    char* As = lds;
    char* Ws = lds + 8192;
    const int tid = threadIdx.x, lane = tid & 63, wv = tid >> 6;
    const int l15 = lane & 15, l4 = lane >> 4;

    int f = tid, ra = f >> 2, ga = (f & 3) ^ ((ra >> 1) & 3);
    const ushort_t* Ag = A + (size_t)(bm * 64 + ra) * K + ga * 8;
    const ushort_t* Wg = W + (size_t)(bn * 64 + ra) * K + ga * 8;

    int aoff, woff[4];
    { int r = wv * 16 + l15; aoff = r * 64 + ((l4 ^ ((r >> 1) & 3)) << 4); }
    #pragma unroll
    for (int n = 0; n < 4; ++n) {
        int cc = n * 16 + l15;
        woff[n] = cc * 64 + ((l4 ^ ((cc >> 1) & 3)) << 4);
    }

    f32x4 acc[4] = {};
    const int nt = K / 32;
    gl2lds16(Ag, As + wv * 1024);
    gl2lds16(Wg, Ws + wv * 1024);

    for (int t = 0; t < nt; ++t) {
        const int buf = t & 1;
        if (t + 1 < nt) {
            const int k1 = (t + 1) * 32;
            gl2lds16(Ag + k1, As + (buf ^ 1) * 4096 + wv * 1024);
            gl2lds16(Wg + k1, Ws + (buf ^ 1) * 4096 + wv * 1024);
            VMCNT(2);
        } else {
            VMCNT(0);
        }
        BARRIER();
        const char* AsB = As + buf * 4096;
        const char* WsB = Ws + buf * 4096;
        short8 fa = *(const short8*)(AsB + aoff);
        short8 fw[4];
        #pragma unroll
        for (int n = 0; n < 4; ++n) fw[n] = *(const short8*)(WsB + woff[n]);
        #pragma unroll
        for (int n = 0; n < 4; ++n) acc[n] = MFMA(fa, fw[n], acc[n]);
        BARRIER();
    }

    const int gr = bm * 64 + wv * 16 + (l4 << 2);
    #pragma unroll
    for (int n = 0; n < 4; ++n) {
        int gc = bn * 64 + n * 16 + l15;
        float bb = bias[gc];
        #pragma unroll
        for (int j = 0; j < 4; ++j)
            C[(size_t)(gr + j) * N + gc] = f2bf(acc[n][j] + bb);
    }
}

// fused audio-proj (blocks 0..255) + q-proj via gemm4 (blocks 256..767)
__global__ __launch_bounds__(256) void fused_aq(
    const ushort_t* __restrict__ afb, const ushort_t* __restrict__ awb,
    const float* __restrict__ a_b, ushort_t* __restrict__ audio,
    const ushort_t* __restrict__ xb, const ushort_t* __restrict__ wqe,
    const float* __restrict__ beff, ushort_t* __restrict__ qbb)
{
    __shared__ char lds[36864];
    const int b = blockIdx.x;
    if (b < 256) {
        audio_body(lds, afb, awb, a_b, audio, b >> 4, b & 15);
    } else {
        const int i = b - 256;                 // 512 q-proj tiles: 32m x 16n
        gemm4_body<0>(lds, xb, wqe, beff, qbb, DIM, DIM, i >> 4, i & 15);
    }
}

// ===========================================================================
// Merged K+V projection (A=audio 1024x1024). grid (32,16): x<16 -> K half
// (row-major out), x>=16 -> V half (transposed out vt[d][key]). r4-validated.
// ===========================================================================
__global__ __launch_bounds__(256) void gemm2_kv(
    const ushort_t* __restrict__ A, const ushort_t* __restrict__ Wk,
    const ushort_t* __restrict__ Wv, const float* __restrict__ bk,
    const float* __restrict__ bv, ushort_t* __restrict__ Ck,
    ushort_t* __restrict__ CvT)
{
    const int K = DIM;
    __shared__ ushort_t As[2][64 * 32];
    __shared__ ushort_t Ws[2][64 * 32];
    const int tid = threadIdx.x, lane = tid & 63, wv = tid >> 6;
    const int l15 = lane & 15, l4 = lane >> 4;
    const int bm = blockIdx.y;
    const bool isV = blockIdx.x >= 16;
    const int bn = blockIdx.x & 15;
    const ushort_t* W = isV ? Wv : Wk;

    int f = tid, ra = f >> 2, ga = (f & 3) ^ ((ra >> 1) & 3);
    const ushort_t* Ag = A + (size_t)(bm * 64 + ra) * K + ga * 8;
    const ushort_t* Wg = W + (size_t)(bn * 64 + ra) * K + ga * 8;

    int aoff, woff[4];
    { int r = wv * 16 + l15; aoff = r * 64 + ((l4 ^ ((r >> 1) & 3)) << 4); }
    #pragma unroll
    for (int n = 0; n < 4; ++n) {
        int cc = n * 16 + l15;
        woff[n] = cc * 64 + ((l4 ^ ((cc >> 1) & 3)) << 4);
    }

    f32x4 acc[4] = {};
    const int nt = K / 32;
    gl2lds16(Ag, (char*)As + wv * 1024);
    gl2lds16(Wg, (char*)Ws + wv * 1024);

    for (int t = 0; t < nt; ++t) {
        const int buf = t & 1;
        if (t + 1 < nt) {
            const int k1 = (t + 1) * 32;
            gl2lds16(Ag + k1, (char*)As + (buf ^ 1) * 4096 + wv * 1024);
            gl2lds16(Wg + k1, (char*)Ws + (buf ^ 1) * 4096 + wv * 1024);
            VMCNT(2);
        } else {
            VMCNT(0);
        }
        BARRIER();
        const char* AsB = (const char*)As + buf * 4096;
        const char* WsB = (const char*)Ws + buf * 4096;
        short8 fa = *(const short8*)(AsB + aoff);
        short8 fw[4];
        #pragma unroll
        for (int n = 0; n < 4; ++n) fw[n] = *(const short8*)(WsB + woff[n]);
        #pragma unroll
        for (int n = 0; n < 4; ++n) acc[n] = MFMA(fa, fw[n], acc[n]);
        BARRIER();
    }

    const int gr = bm * 64 + wv * 16 + (l4 << 2);
    #pragma unroll
    for (int n = 0; n < 4; ++n) {
        int gc = bn * 64 + n * 16 + l15;
        float bb = (isV ? bv : bk)[gc];
        if (!isV) {
            #pragma unroll
            for (int j = 0; j < 4; ++j)
                Ck[(size_t)(gr + j) * DIM + gc] = f2bf(acc[n][j] + bb);
        } else {
            ushort4 o = { f2bf(acc[n][0] + bb), f2bf(acc[n][1] + bb),
                          f2bf(acc[n][2] + bb), f2bf(acc[n][3] + bb) };
            *(ushort4*)(CvT + (size_t)gc * DIM + gr) = o;
        }
    }
}

// ===========================================================================
// attn3 (r8-validated, 43.5us): no-max flash attention, Q pre-scaled,
// P = exp2(S); P->bf16 via v_cvt_pk_bf16_f32. Ps overlays dead Qs. 40KB LDS.
// ===========================================================================
__global__ __launch_bounds__(256) void attn3(
    const ushort_t* __restrict__ Qf, const ushort_t* __restrict__ Kf,
    const ushort_t* __restrict__ Vt, ushort_t* __restrict__ AO)
{
    __shared__ char lds[40960];
    char* QsPs = lds;
    char* KsB0 = lds + 8192;
    char* VsB0 = lds + 24576;

    const int tid = threadIdx.x, lane = tid & 63, wv = tid >> 6;
    const int l15 = lane & 15, l4 = lane >> 4;
    const int h = blockIdx.y, qb = blockIdx.x;

    #pragma unroll
    for (int i = 0; i < 2; ++i) {
        int f = i * 256 + tid, q = f >> 3, s = (f & 7) ^ (q & 7);
        gl2lds16(Qf + (size_t)(qb * 64 + q) * DIM + h * HD + s * 8,
                 QsPs + i * 4096 + wv * 1024);
    }
    const int f0 = tid, r0 = f0 >> 3, s0 = (f0 & 7) ^ (r0 & 7);
    const int f1 = 256 + tid, r1 = f1 >> 3, s1 = (f1 & 7) ^ (r1 & 7);
    const ushort_t* Kg0 = Kf + (size_t)r0 * DIM + h * HD + s0 * 8;
    const ushort_t* Kg1 = Kf + (size_t)r1 * DIM + h * HD + s1 * 8;
    const ushort_t* Vg0 = Vt + (size_t)(h * HD + r0) * DIM + s0 * 8;
    const ushort_t* Vg1 = Vt + (size_t)(h * HD + r1) * DIM + s1 * 8;

    int qoff[2], koff[4][2], poff[2];
    #pragma unroll
    for (int ks = 0; ks < 2; ++ks) {
        int r = wv * 16 + l15;
        qoff[ks] = r * 128 + (((ks * 4 + l4) ^ (r & 7)) << 4);
        poff[ks] = wv * 2048 + l15 * 128 + (((ks * 4 + l4) ^ (l15 & 7)) << 4);
    }
    #pragma unroll
    for (int n = 0; n < 4; ++n) {
        int kk = n * 16 + l15;
        #pragma unroll
        for (int ks = 0; ks < 2; ++ks)
            koff[n][ks] = kk * 128 + (((ks * 4 + l4) ^ (kk & 7)) << 4);
    }

    f32x4 acc_o[4] = {};
    float l_loc[4] = {0.f, 0.f, 0.f, 0.f};

    gl2lds16(Kg0, KsB0 + wv * 1024);
    gl2lds16(Kg1, KsB0 + 4096 + wv * 1024);
    gl2lds16(Vg0, VsB0 + wv * 1024);
    gl2lds16(Vg1, VsB0 + 4096 + wv * 1024);
    VMCNT(4);
    BARRIER();
    short8 fq[2];
    #pragma unroll
    for (int ks = 0; ks < 2; ++ks)
        fq[ks] = *(const short8*)(QsPs + qoff[ks]);

    for (int t = 0; t < 16; ++t) {
        const int buf = t & 1;
        if (t < 15) {
            gl2lds16(Kg0 + (size_t)(t + 1) * 64 * DIM,
                     KsB0 + (buf ^ 1) * 8192 + wv * 1024);
            gl2lds16(Kg1 + (size_t)(t + 1) * 64 * DIM,
                     KsB0 + (buf ^ 1) * 8192 + 4096 + wv * 1024);
            gl2lds16(Vg0 + (t + 1) * 64,
                     VsB0 + (buf ^ 1) * 8192 + wv * 1024);
            gl2lds16(Vg1 + (t + 1) * 64,
                     VsB0 + (buf ^ 1) * 8192 + 4096 + wv * 1024);
            VMCNT(4);
        } else {
            VMCNT(0);
        }
        BARRIER();

        const char* KsT = KsB0 + buf * 8192;
        const char* VsT = VsB0 + buf * 8192;

        f32x4 s_acc[4] = {};
        short8 fk[4][2];
        #pragma unroll
        for (int n = 0; n < 4; ++n)
            #pragma unroll
            for (int ks = 0; ks < 2; ++ks)
                fk[n][ks] = *(const short8*)(KsT + koff[n][ks]);
        #pragma unroll
        for (int n = 0; n < 4; ++n)
            #pragma unroll
            for (int ks = 0; ks < 2; ++ks)
                s_acc[n] = MFMA(fq[ks], fk[n][ks], s_acc[n]);

        #pragma unroll
        for (int j = 0; j < 4; ++j) {
            float p0 = exp2f(s_acc[0][j]);
            float p1 = exp2f(s_acc[1][j]);
            float p2 = exp2f(s_acc[2][j]);
            float p3 = exp2f(s_acc[3][j]);
            l_loc[j] += (p0 + p1) + (p2 + p3);
            unsigned pk01, pk23;
            asm("v_cvt_pk_bf16_f32 %0, %1, %2" : "=v"(pk01) : "v"(p0), "v"(p1));
            asm("v_cvt_pk_bf16_f32 %0, %1, %2" : "=v"(pk23) : "v"(p2), "v"(p3));
            int r16 = (l4 << 2) + j;
            int basb = wv * 2048 + r16 * 128;
            int sw = (r16 & 7) << 4;
            int kx = l15 * 2;
            *(ushort_t*)(QsPs + basb + ((kx) ^ sw))      = (ushort_t)pk01;
            *(ushort_t*)(QsPs + basb + ((32 + kx) ^ sw)) = (ushort_t)(pk01 >> 16);
            *(ushort_t*)(QsPs + basb + ((64 + kx) ^ sw)) = (ushort_t)pk23;
            *(ushort_t*)(QsPs + basb + ((96 + kx) ^ sw)) = (ushort_t)(pk23 >> 16);
        }

        short8 pa[2], fv[4][2];
        #pragma unroll
        for (int ks = 0; ks < 2; ++ks)
            pa[ks] = *(const short8*)(QsPs + poff[ks]);
        #pragma unroll
        for (int n = 0; n < 4; ++n)
            #pragma unroll
            for (int ks = 0; ks < 2; ++ks)
                fv[n][ks] = *(const short8*)(VsT + koff[n][ks]);
        #pragma unroll
        for (int dn = 0; dn < 4; ++dn)
            #pragma unroll
            for (int ks = 0; ks < 2; ++ks)
                acc_o[dn] = MFMA(pa[ks], fv[dn][ks], acc_o[dn]);
        BARRIER();
    }

    #pragma unroll
    for (int j = 0; j < 4; ++j) {
        float l = l_loc[j];
        l += __shfl_xor(l, 1);
        l += __shfl_xor(l, 2);
        l += __shfl_xor(l, 4);
        l += __shfl_xor(l, 8);
        float inv = 1.0f / l;
        int q = qb * 64 + wv * 16 + (l4 << 2) + j;
        #pragma unroll
        for (int dn = 0; dn < 4; ++dn)
            AO[(size_t)q * DIM + h * HD + dn * 16 + l15] =
                f2bf(acc_o[dn][j] * inv);
    }
}

// ===========================================================================
extern "C" void kernel_launch(void* const* d_in, const int* in_sizes, int n_in,
                              void* d_out, int out_size, void* d_ws, size_t ws_size,
                              hipStream_t stream)
{
    const float* x   = (const float*)d_in[0];
    const float* af  = (const float*)d_in[1];
    const float* q_w = (const float*)d_in[2];
    const float* q_b = (const float*)d_in[3];
    const float* k_w = (const float*)d_in[4];
    const float* k_b = (const float*)d_in[5];
    const float* v_w = (const float*)d_in[6];
    const float* v_b = (const float*)d_in[7];
    const float* o_w = (const float*)d_in[8];
    const float* o_b = (const float*)d_in[9];
    const float* a_w = (const float*)d_in[10];
    const float* a_b = (const float*)d_in[11];
    const float* qA  = (const float*)d_in[12];
    const float* qB  = (const float*)d_in[13];
    const float* kA  = (const float*)d_in[14];
    const float* kB  = (const float*)d_in[15];
    const float* vA  = (const float*)d_in[16];
    const float* vB  = (const float*)d_in[17];
    float* out = (float*)d_out;

    const int N = 4096;

    char* w = (char*)d_ws;
    auto alloc = [&](size_t bytes) {
        char* p = w; w += (bytes + 255) & ~(size_t)255; return p;
    };
    ushort_t* xb   = (ushort_t*)alloc((size_t)N * DIM * 2);
    ushort_t* afb  = (ushort_t*)alloc((size_t)1024 * 768 * 2);
    ushort_t* awb  = (ushort_t*)alloc((size_t)DIM * 768 * 2);
    ushort_t* owb  = (ushort_t*)alloc((size_t)DIM * DIM * 2);
    ushort_t* wqe  = (ushort_t*)alloc((size_t)DIM * DIM * 2);
    ushort_t* wke  = (ushort_t*)alloc((size_t)DIM * DIM * 2);
    ushort_t* wve  = (ushort_t*)alloc((size_t)DIM * DIM * 2);
    ushort_t* audio= (ushort_t*)alloc((size_t)1024 * DIM * 2);
    ushort_t* qbb  = (ushort_t*)alloc((size_t)N * DIM * 2);
    ushort_t* kbb  = (ushort_t*)alloc((size_t)1024 * DIM * 2);
    ushort_t* vt   = (ushort_t*)alloc((size_t)1024 * DIM * 2);
    ushort_t* ao   = (ushort_t*)alloc((size_t)N * DIM * 2);
    float* part = (float*)alloc((size_t)48 * 4 * 1024 * 4);
    float* beff = (float*)alloc((size_t)3 * 1024 * 4);

    // 1. T1 partials (first) + conversions
    prep1<<<6704, 256, 0, stream>>>(
        x, af, a_w, o_w, xb, afb, awb, owb,
        q_w, k_w, v_w, qA, kA, vA, part);
    // 2. LoRA weight fold apply (QSCALE folded into q)
    prep2<<<48, 256, 0, stream>>>(
        q_w, k_w, v_w, qA, kA, vA, qB, kB, vB, q_b, k_b, v_b,
        part, wqe, wke, wve, beff);
    // 3. audio projection (blocks 0-255) || q projection (blocks 256-767)
    fused_aq<<<768, 256, 0, stream>>>(afb, awb, a_b, audio, xb, wqe, beff, qbb);
    // 4. k,v projections (v transposed)
    gemm2_kv<<<dim3(32, 16), 256, 0, stream>>>(audio, wke, wve,
                                               beff + 1024, beff + 2048, kbb, vt);
    // 5. attention (r8-validated attn3)
    attn3<<<dim3(N / 64, HEADS), 256, 0, stream>>>(qbb, kbb, vt, ao);
    // 6. output projection (f32 out, gemm4 128x64 tiles, 512 blocks)
    gemm4<1><<<dim3(16, 32), 256, 0, stream>>>(ao, owb, o_b, out, DIM, DIM);
}